// Round 8
// baseline (210.668 us; speedup 1.0000x reference)
//
#include <hip/hip_runtime.h>
#include <hip/hip_bf16.h>

#define THREADS 512
#define ROWS 64
#define NPAD 67456          // 65536 + 128*15 : max padded row-slot count (buckets 16-aligned)
#define NBLK 1054           // NPAD / 64

typedef __attribute__((ext_vector_type(4))) float f32x4;
typedef __attribute__((ext_vector_type(8))) short s16x8;

__device__ __forceinline__ unsigned short bfbits(float f) {
  __bf16 h = (__bf16)f;
  return __builtin_bit_cast(unsigned short, h);
}

// ---------------- prep: pack weights into MFMA A-fragment order (bf16) ----------------
// A-frag for mfma_f32_16x16x32_bf16: lane l holds A[m=l&15][k=(l>>4)*8+j], j=0..7
// w1f: [c:12][ft:32][lane:64][8]   (K=384 of W1; k=384 is a rank-1 term in epilogue 1)
// w2f: [c:16][ft:16][lane:64][8]
// w3f: [c: 8][ft:12][lane:64][8]
// whf: [head:128][c:6][lane:64][8]   (Wh[head] as A-frags over K=192, j-dim = 16 outputs)
__global__ void prep_kernel(const float* __restrict__ W1, const float* __restrict__ W2,
                            const float* __restrict__ W3, const float* __restrict__ Wh,
                            unsigned short* __restrict__ w1f, unsigned short* __restrict__ w2f,
                            unsigned short* __restrict__ w3f, unsigned short* __restrict__ whf) {
  int u = blockIdx.x * blockDim.x + threadIdx.x;
  const int U1 = 24576, U2 = 16384, U3 = 6144, U4 = 49152;
  if (u < U1) {                                   // W1 frags
    int lane = u & 63, r = (u >> 6) & 31, c = u >> 11;
    int f  = r * 16 + (lane & 15);
    int kb = c * 32 + ((lane >> 4) << 3);
    s16x8 v;
    #pragma unroll
    for (int j = 0; j < 8; ++j) v[j] = (short)bfbits(W1[(kb + j) * 512 + f]);
    *(s16x8*)(w1f + (u << 3)) = v;
    return;
  }
  u -= U1;
  if (u < U2) {                                   // W2 frags
    int lane = u & 63, r = (u >> 6) & 15, c = u >> 10;
    int f  = r * 16 + (lane & 15);
    int kb = c * 32 + ((lane >> 4) << 3);
    s16x8 v;
    #pragma unroll
    for (int j = 0; j < 8; ++j) v[j] = (short)bfbits(W2[(kb + j) * 256 + f]);
    *(s16x8*)(w2f + (u << 3)) = v;
    return;
  }
  u -= U2;
  if (u < U3) {                                   // W3 frags
    int lane = u & 63, t = u >> 6;
    int c = t / 12, r = t - c * 12;
    int f  = r * 16 + (lane & 15);
    int kb = c * 32 + ((lane >> 4) << 3);
    s16x8 v;
    #pragma unroll
    for (int j = 0; j < 8; ++j) v[j] = (short)bfbits(W3[(kb + j) * 192 + f]);
    *(s16x8*)(w3f + (u << 3)) = v;
    return;
  }
  u -= U3;
  if (u < U4) {                                   // Wh A-frags per head
    int lane = u & 63, t = u >> 6;                // t = head*6 + c
    int c = t % 6, head = t / 6;
    int kb = c * 32 + ((lane >> 4) << 3);
    s16x8 v;
    #pragma unroll
    for (int j = 0; j < 8; ++j)
      v[j] = (short)bfbits(Wh[(size_t)(kb + j) * 2048 + head * 16 + (lane & 15)]);
    *(s16x8*)(whf + (u << 3)) = v;
  }
}

// ---------------- sort rows by head (128 buckets, 16-aligned) ----------------
__global__ void hist_init_kernel(const int* __restrict__ qid, const int* __restrict__ corr,
                                 int* __restrict__ cnt, int* __restrict__ rowmap) {
  int i = blockIdx.x * blockDim.x + threadIdx.x;
  if (i < NPAD) rowmap[i] = (int)0x80000000;      // pad sentinel
  if (i < 65536) atomicAdd(&cnt[qid[i] * 2 + corr[i]], 1);
}

__global__ void prefix_kernel(const int* __restrict__ cnt, int* __restrict__ cursor) {
  __shared__ int s[128];
  int t = threadIdx.x;                            // 128 threads
  int padded = (cnt[t] + 15) & ~15;
  s[t] = padded;
  __syncthreads();
  int acc = padded;
  for (int d = 1; d < 128; d <<= 1) {
    int v = (t >= d) ? s[t - d] : 0;
    __syncthreads();
    acc += v;
    s[t] = acc;
    __syncthreads();
  }
  cursor[t] = acc - padded;                       // exclusive prefix of padded counts
}

__global__ void scatter_kernel(const int* __restrict__ qid, const int* __restrict__ corr,
                               int* __restrict__ cursor, int* __restrict__ rowmap) {
  int i = blockIdx.x * blockDim.x + threadIdx.x;
  if (i < 65536) {
    int h = qid[i] * 2 + corr[i];
    int pos = atomicAdd(&cursor[h], 1);           // order within bucket irrelevant
    rowmap[pos] = i;
  }
}

// ---------------- fused MLP: 64 sorted rows/block, 512 threads, 2 blocks/CU ----------------
// LDS = 81920 B. Region rotation:
//   @0     48K : xall (12 x-chunks) -> h1L (h1 f256..511 frags, 32K) -> h3f (6 chunks, 24K)
//   @49152 32K : h1H (h1 f0..255 frags) -> h2f (GEMM3 B-frags)
// Head layer: rows sorted by head -> each 16-row tile is single-head -> 6 MFMAs/tile with
// shared Wh A-frags (whf), un-permuted scatter store at the end.
#define MFMA(a, b, c) __builtin_amdgcn_mfma_f32_16x16x32_bf16((a), (b), (c), 0, 0, 0)
#define SWZ(lp) (((lp) * 16) ^ ((((lp) >> 4) & 3) << 5))

#define G1_RANGE(P, C0, C1)                                                                 \
  _Pragma("unroll")                                                                         \
  for (int c = (C0); c < (C1); ++c) {                                                       \
    s16x8 a0 = *(const s16x8*)(w1f + (((c * 32 + (P) * 16 + w * 2 + 0) * 64 + lane) << 3)); \
    s16x8 a1 = *(const s16x8*)(w1f + (((c * 32 + (P) * 16 + w * 2 + 1) * 64 + lane) << 3)); \
    _Pragma("unroll")                                                                       \
    for (int bt = 0; bt < 4; ++bt) {                                                        \
      s16x8 bfr = *(const s16x8*)(xall + (c << 12) + (bt << 10) + swz_l);                   \
      acc1[0][bt] = MFMA(a0, bfr, acc1[0][bt]);                                             \
      acc1[1][bt] = MFMA(a1, bfr, acc1[1][bt]);                                             \
    }                                                                                       \
  }

__global__ __launch_bounds__(THREADS, 4)
void fused_mlp(const float* __restrict__ x,
               const float* __restrict__ b1,
               const float* __restrict__ b2,
               const float* __restrict__ b3,
               const float* __restrict__ bh,
               const float* __restrict__ W1,
               const int* __restrict__ qid,
               const int* __restrict__ corr,
               const int* __restrict__ rowmap,
               const unsigned short* __restrict__ w1f,
               const unsigned short* __restrict__ w2f,
               const unsigned short* __restrict__ w3f,
               const unsigned short* __restrict__ whf,
               float* __restrict__ out) {
  __shared__ __align__(16) unsigned char lds[81920];
  unsigned char*  xall = lds;                             // GEMM1 B-frags (12 x 4K)
  unsigned char*  h1L  = lds;                             // h1 f256..511 frags (alias xall)
  unsigned char*  h3f  = lds;                             // h3 B-frags, 6 chunks (alias, last)
  unsigned char*  h1H  = lds + 49152;                     // h1 f0..255 frags (32K)
  unsigned char*  h2f  = lds + 49152;                     // GEMM3 B-frags (alias h1H)

  const int tid  = threadIdx.x;
  const int lane = tid & 63;
  const int w    = tid >> 6;     // wave 0..7
  const int b0   = blockIdx.x * ROWS;
  const int l15  = lane & 15;
  const int lh   = lane >> 4;    // 0..3
  const int swz_l = SWZ(lane);

  // per-row-tile x offsets for the rank-1 column (epilogue 1), via rowmap
  int xro[4];
  #pragma unroll
  for (int bt = 0; bt < 4; ++bt)
    xro[bt] = (rowmap[b0 + (bt << 4) + l15] & 0x7FFFFFFF) * 385;

  // ---- x staging: 6 groups x 2 chunks; ONE 16B frag per thread per group ----
  const int s_ci = tid >> 8;                       // chunk parity in group (0..1)
  const int s_wi = tid & 255;
  const int s_bt = s_wi >> 6;                      // 0..3
  const int s_lp = s_wi & 63;
  const int s_xrow = rowmap[b0 + (s_bt << 4) + (s_lp & 15)] & 0x7FFFFFFF;
  const float* s_base = x + (size_t)s_xrow * 385 + ((s_lp >> 4) << 3);
  const int s_abase = (s_bt << 10) + SWZ(s_lp);

  f32x4 sv0, sv1;
  auto sload = [&](int g) {
    int c = (g << 1) + s_ci;
    sv0 = *(const f32x4*)(s_base + c * 32);
    sv1 = *(const f32x4*)(s_base + c * 32 + 4);
  };
  auto swrite = [&](int g) {
    int c = (g << 1) + s_ci;
    s16x8 v;
    v[0] = (short)bfbits(sv0[0]); v[1] = (short)bfbits(sv0[1]);
    v[2] = (short)bfbits(sv0[2]); v[3] = (short)bfbits(sv0[3]);
    v[4] = (short)bfbits(sv1[0]); v[5] = (short)bfbits(sv1[1]);
    v[6] = (short)bfbits(sv1[2]); v[7] = (short)bfbits(sv1[3]);
    *(s16x8*)(xall + (c << 12) + s_abase) = v;
  };

  f32x4 acc1[2][4];
  #pragma unroll
  for (int a = 0; a < 2; ++a)
    #pragma unroll
    for (int bt = 0; bt < 4; ++bt) acc1[a][bt] = (f32x4)0.0f;

  // epilogue 1 (pass P -> dst): rank-1 (k=384) + bias + relu -> bf16 B-frags; reset acc1
  auto epi1 = [&](int P, unsigned char* dst) {
    #pragma unroll
    for (int a = 0; a < 2; ++a) {
      int ft = w * 2 + a;                           // f-tile within pass, 0..15
      int fg = P * 256 + (ft << 4) + (lh << 2);
      f32x4 bv = *(const f32x4*)(b1 + fg);
      f32x4 wv = *(const f32x4*)(W1 + 384 * 512 + fg);
      int so = ((ft >> 1) << 12) + SWZ(l15 + ((((ft & 1) << 1) + (lh >> 1)) << 4)) + ((lh & 1) << 3);
      #pragma unroll
      for (int bt = 0; bt < 4; ++bt) {
        float xv = x[(size_t)xro[bt] + 384];        // L1-hot rank-1 column (mapped row)
        float v0 = fmaxf(acc1[a][bt][0] + bv[0] + wv[0] * xv, 0.f);
        float v1 = fmaxf(acc1[a][bt][1] + bv[1] + wv[1] * xv, 0.f);
        float v2 = fmaxf(acc1[a][bt][2] + bv[2] + wv[2] * xv, 0.f);
        float v3 = fmaxf(acc1[a][bt][3] + bv[3] + wv[3] * xv, 0.f);
        unsigned plo = (unsigned)bfbits(v0) | ((unsigned)bfbits(v1) << 16);
        unsigned phi = (unsigned)bfbits(v2) | ((unsigned)bfbits(v3) << 16);
        unsigned long long pk = (unsigned long long)plo | ((unsigned long long)phi << 32);
        *(unsigned long long*)(dst + so + (bt << 10)) = pk;
        acc1[a][bt] = (f32x4)0.0f;
      }
    }
  };

  // ---- GEMM1 pass 1 (f 0..255) pipelined with x staging (2 chunks/phase) ----
  sload(0); swrite(0);
  __syncthreads();                       // chunks 0,1 staged

  sload(1); G1_RANGE(0, 0, 2)  swrite(1); __syncthreads();
  sload(2); G1_RANGE(0, 2, 4)  swrite(2); __syncthreads();
  sload(3); G1_RANGE(0, 4, 6)  swrite(3); __syncthreads();
  sload(4); G1_RANGE(0, 6, 8)  swrite(4); __syncthreads();
  sload(5); G1_RANGE(0, 8, 10) swrite(5); __syncthreads();

  G1_RANGE(0, 10, 12)
  epi1(0, h1H);                          // h1 f0..255 -> h1H (fresh region, no hazard)

  // ---- GEMM1 pass 2 (f 256..511); xall fully resident, barrier-free ----
  G1_RANGE(1, 0, 12)
  __syncthreads();                       // B7: all xall reads done; h1H writes visible
  epi1(1, h1L);                          // h1 f256..511 -> h1L (first 32K of dead xall)
  __syncthreads();                       // B8: h1L visible

  // ---- GEMM2: h2^T[256f x 64b] = W2^T h1^T, K=512 ----
  f32x4 acc2[2][4];
  #pragma unroll
  for (int i = 0; i < 2; ++i)
    #pragma unroll
    for (int bt = 0; bt < 4; ++bt) acc2[i][bt] = (f32x4)0.0f;

  #pragma unroll
  for (int c = 0; c < 16; ++c) {
    const unsigned char* reg = (c < 8) ? h1H : h1L;
    int cl = c & 7;
    s16x8 a20 = *(const s16x8*)(w2f + (((c * 16 + w * 2 + 0) * 64 + lane) << 3));
    s16x8 a21 = *(const s16x8*)(w2f + (((c * 16 + w * 2 + 1) * 64 + lane) << 3));
    #pragma unroll
    for (int bt = 0; bt < 4; ++bt) {
      s16x8 bfr = *(const s16x8*)(reg + (cl << 12) + (bt << 10) + swz_l);
      acc2[0][bt] = MFMA(a20, bfr, acc2[0][bt]);
      acc2[1][bt] = MFMA(a21, bfr, acc2[1][bt]);
    }
  }
  __syncthreads();                       // B9: h1H + h1L reads done

  // epilogue 2 -> h2f (h1H region)
  #pragma unroll
  for (int i = 0; i < 2; ++i) {
    int ft = w * 2 + i;
    int fg = (ft << 4) + (lh << 2);
    f32x4 bv = *(const f32x4*)(b2 + fg);
    int so = ((ft >> 1) << 12) + SWZ(l15 + ((((ft & 1) << 1) + (lh >> 1)) << 4)) + ((lh & 1) << 3);
    #pragma unroll
    for (int bt = 0; bt < 4; ++bt) {
      float v0 = fmaxf(acc2[i][bt][0] + bv[0], 0.f);
      float v1 = fmaxf(acc2[i][bt][1] + bv[1], 0.f);
      float v2 = fmaxf(acc2[i][bt][2] + bv[2], 0.f);
      float v3 = fmaxf(acc2[i][bt][3] + bv[3], 0.f);
      unsigned plo = (unsigned)bfbits(v0) | ((unsigned)bfbits(v1) << 16);
      unsigned phi = (unsigned)bfbits(v2) | ((unsigned)bfbits(v3) << 16);
      unsigned long long pk = (unsigned long long)plo | ((unsigned long long)phi << 32);
      *(unsigned long long*)(h2f + so + (bt << 10)) = pk;
    }
  }
  __syncthreads();                       // B10: h2f visible

  // ---- GEMM3: h3^T[192f x 64b] = W3^T h2^T, K=256; 12 f-tiles over 8 waves ----
  {
    f32x4 acc3[2][4];
    #pragma unroll
    for (int i = 0; i < 2; ++i)
      #pragma unroll
      for (int bt = 0; bt < 4; ++bt) acc3[i][bt] = (f32x4)0.0f;

    #pragma unroll
    for (int c = 0; c < 8; ++c) {
      s16x8 a30 = *(const s16x8*)(w3f + (((c * 12 + w) * 64 + lane) << 3));
      s16x8 a31;
      if (w < 4) a31 = *(const s16x8*)(w3f + (((c * 12 + 8 + w) * 64 + lane) << 3));
      #pragma unroll
      for (int bt = 0; bt < 4; ++bt) {
        s16x8 bfr = *(const s16x8*)(h2f + (c << 12) + (bt << 10) + swz_l);
        acc3[0][bt] = MFMA(a30, bfr, acc3[0][bt]);
        if (w < 4) acc3[1][bt] = MFMA(a31, bfr, acc3[1][bt]);
      }
    }
    // epilogue 3 -> h3f B-frags (6 chunks over K=192) @0; that region's reads ended at B9
    #pragma unroll
    for (int i = 0; i < 2; ++i) {
      if (i == 0 || w < 4) {
        int ft = (i == 0) ? w : (8 + w);
        int fg = (ft << 4) + (lh << 2);
        f32x4 bv = *(const f32x4*)(b3 + fg);
        int so = ((ft >> 1) << 12) + SWZ(l15 + ((((ft & 1) << 1) + (lh >> 1)) << 4)) + ((lh & 1) << 3);
        #pragma unroll
        for (int bt = 0; bt < 4; ++bt) {
          float v0 = fmaxf(acc3[i][bt][0] + bv[0], 0.f);
          float v1 = fmaxf(acc3[i][bt][1] + bv[1], 0.f);
          float v2 = fmaxf(acc3[i][bt][2] + bv[2], 0.f);
          float v3 = fmaxf(acc3[i][bt][3] + bv[3], 0.f);
          unsigned plo = (unsigned)bfbits(v0) | ((unsigned)bfbits(v1) << 16);
          unsigned phi = (unsigned)bfbits(v2) | ((unsigned)bfbits(v3) << 16);
          unsigned long long pk = (unsigned long long)plo | ((unsigned long long)phi << 32);
          *(unsigned long long*)(h3f + so + (bt << 10)) = pk;
        }
      }
    }
  }
  __syncthreads();                       // B11: h3f ready

  // ---- head: sorted rows -> each 16-row tile single-head; waves 0..3, tile = w ----
  if (w < 4) {
    int ts  = b0 + (w << 4);
    int rm0 = rowmap[ts];                          // first row of tile: real unless tile all-pad
    int r0  = rm0 & 0x7FFFFFFF;
    int head = qid[r0] * 2 + corr[r0];
    f32x4 acch = (f32x4)0.0f;
    #pragma unroll
    for (int c = 0; c < 6; ++c) {
      s16x8 ah  = *(const s16x8*)(whf + (((head * 6 + c) * 64 + lane) << 3));
      s16x8 bfr = *(const s16x8*)(h3f + (c << 12) + (w << 10) + swz_l);
      acch = MFMA(ah, bfr, acch);
    }
    // D[j][row]: col = lane&15 = row-in-tile, j = lh*4 + i; un-permute via rowmap
    int rs = rowmap[ts + l15];
    if (!(rs & 0x80000000)) {
      f32x4 bv = *(const f32x4*)(bh + (head << 4) + (lh << 2));
      f32x4 ov;
      ov[0] = acch[0] + bv[0]; ov[1] = acch[1] + bv[1];
      ov[2] = acch[2] + bv[2]; ov[3] = acch[3] + bv[3];
      *(f32x4*)(out + (size_t)rs * 16 + (lh << 2)) = ov;
    }
  }
}

extern "C" void kernel_launch(void* const* d_in, const int* in_sizes, int n_in,
                              void* d_out, int out_size, void* d_ws, size_t ws_size,
                              hipStream_t stream) {
  (void)in_sizes; (void)n_in; (void)out_size; (void)ws_size;
  const float* x  = (const float*)d_in[0];
  const float* W1 = (const float*)d_in[1];
  const float* b1 = (const float*)d_in[2];
  const float* W2 = (const float*)d_in[3];
  const float* b2 = (const float*)d_in[4];
  const float* W3 = (const float*)d_in[5];
  const float* b3 = (const float*)d_in[6];
  const float* Wh = (const float*)d_in[7];
  const float* bh = (const float*)d_in[8];
  const int* qid  = (const int*)d_in[9];
  const int* corr = (const int*)d_in[10];
  float* out = (float*)d_out;

  unsigned short* w1f = (unsigned short*)d_ws;     // 196608 bf16
  unsigned short* w2f = w1f + 196608;              // 131072
  unsigned short* w3f = w2f + 131072;              // 49152
  unsigned short* whf = w3f + 49152;               // 393216  (weights total ~1.54 MB)
  int* cnt    = (int*)(whf + 393216);              // 128
  int* cursor = cnt + 128;                         // 128
  int* rowmap = cursor + 128;                      // NPAD ints (~270 KB) -> ws total ~1.81 MB

  hipMemsetAsync(cnt, 0, 128 * sizeof(int), stream);
  prep_kernel<<<376, 256, 0, stream>>>(W1, W2, W3, Wh, w1f, w2f, w3f, whf);
  hist_init_kernel<<<(NPAD + 255) / 256, 256, 0, stream>>>(qid, corr, cnt, rowmap);
  prefix_kernel<<<1, 128, 0, stream>>>(cnt, cursor);
  scatter_kernel<<<256, 256, 0, stream>>>(qid, corr, cursor, rowmap);
  fused_mlp<<<NBLK, THREADS, 0, stream>>>(x, b1, b2, b3, bh, W1, qid, corr, rowmap,
                                          w1f, w2f, w3f, whf, out);
}

// Round 9
// 145.138 us; speedup vs baseline: 1.4515x; 1.4515x over previous
//
#include <hip/hip_runtime.h>
#include <hip/hip_bf16.h>

#define THREADS 512
#define ROWS 64

typedef __attribute__((ext_vector_type(4))) float f32x4;
typedef __attribute__((ext_vector_type(8))) short s16x8;

__device__ __forceinline__ unsigned short bfbits(float f) {
  __bf16 h = (__bf16)f;
  return __builtin_bit_cast(unsigned short, h);
}
__device__ __forceinline__ float bf2f(unsigned short h) {
  unsigned u = ((unsigned)h) << 16;
  return __builtin_bit_cast(float, u);
}

// ---------------- prep: pack weights into MFMA A-fragment order (bf16) ----------------
// A-frag for mfma_f32_16x16x32_bf16: lane l holds A[m=l&15][k=(l>>4)*8+j], j=0..7
// w1f: [c:12][ft:32][lane:64][8]   (K=384 of W1; k=384 is a rank-1 term in epilogue 1)
// w2f: [c:16][ft:16][lane:64][8]
// w3f: [c: 8][ft:12][lane:64][8]
// whT: [head:128][fo:24][j:16][8] bf16  (head gathers 256B-contiguous per 16-lane group)
__global__ void prep_kernel(const float* __restrict__ W1, const float* __restrict__ W2,
                            const float* __restrict__ W3, const float* __restrict__ Wh,
                            unsigned short* __restrict__ w1f, unsigned short* __restrict__ w2f,
                            unsigned short* __restrict__ w3f, unsigned short* __restrict__ whT) {
  int u = blockIdx.x * blockDim.x + threadIdx.x;
  const int U1 = 24576, U2 = 16384, U3 = 6144, U4 = 49152;
  if (u < U1) {                                   // W1 frags
    int lane = u & 63, r = (u >> 6) & 31, c = u >> 11;
    int f  = r * 16 + (lane & 15);
    int kb = c * 32 + ((lane >> 4) << 3);
    s16x8 v;
    #pragma unroll
    for (int j = 0; j < 8; ++j) v[j] = (short)bfbits(W1[(kb + j) * 512 + f]);
    *(s16x8*)(w1f + (u << 3)) = v;
    return;
  }
  u -= U1;
  if (u < U2) {                                   // W2 frags
    int lane = u & 63, r = (u >> 6) & 15, c = u >> 10;
    int f  = r * 16 + (lane & 15);
    int kb = c * 32 + ((lane >> 4) << 3);
    s16x8 v;
    #pragma unroll
    for (int j = 0; j < 8; ++j) v[j] = (short)bfbits(W2[(kb + j) * 256 + f]);
    *(s16x8*)(w2f + (u << 3)) = v;
    return;
  }
  u -= U2;
  if (u < U3) {                                   // W3 frags
    int lane = u & 63, t = u >> 6;
    int c = t / 12, r = t - c * 12;
    int f  = r * 16 + (lane & 15);
    int kb = c * 32 + ((lane >> 4) << 3);
    s16x8 v;
    #pragma unroll
    for (int j = 0; j < 8; ++j) v[j] = (short)bfbits(W3[(kb + j) * 192 + f]);
    *(s16x8*)(w3f + (u << 3)) = v;
    return;
  }
  u -= U3;
  if (u < U4) {                                   // Wh -> [head][fo][j][8]
    int j = u & 15, v2 = u >> 4;
    int fo = v2 % 24, head = v2 / 24;
    s16x8 v;
    #pragma unroll
    for (int i = 0; i < 8; ++i) v[i] = (short)bfbits(Wh[(fo * 8 + i) * 2048 + head * 16 + j]);
    *(s16x8*)(whT + u * 8) = v;
  }
}

// ---------------- fused MLP: wave-independent pipeline, 4 barriers ----------------
// 512 threads = 8 waves; wave w: row-tile rt = w&3 (16 rows), f-half fh = w>>2.
// x lives in REGISTERS (12 B-frag chunks, 48 VGPRs) -> GEMM1 is barrier-free.
// LDS (65536 B -> 2 blocks/CU):
//   h1B: rt*16384 + c2*1024  (c2 0..15; fh 0 writes c2 0..7, fh 1 writes 8..15)
//   h2B: rt*8192  + c2*1024  (c2 0..7; overwrites h1B area after B2)
//   h3b: @36864, [rt][row:16][200] bf16
#define MFMA(a, b, c) __builtin_amdgcn_mfma_f32_16x16x32_bf16((a), (b), (c), 0, 0, 0)
#define SWZ(lp) (((lp) * 16) ^ ((((lp) >> 4) & 3) << 5))

__global__ __launch_bounds__(THREADS, 4)
void fused_mlp(const float* __restrict__ x,
               const float* __restrict__ b1,
               const float* __restrict__ b2,
               const float* __restrict__ b3,
               const float* __restrict__ bh,
               const float* __restrict__ W1,
               const int* __restrict__ qid,
               const int* __restrict__ corr,
               const unsigned short* __restrict__ w1f,
               const unsigned short* __restrict__ w2f,
               const unsigned short* __restrict__ w3f,
               const unsigned short* __restrict__ whT,
               float* __restrict__ out) {
  __shared__ __align__(16) unsigned char lds[65536];

  const int tid  = threadIdx.x;
  const int lane = tid & 63;
  const int w    = tid >> 6;       // wave 0..7
  const int rt   = w & 3;          // row-tile 0..3
  const int fh   = w >> 2;         // f-half 0..1
  const int b0   = blockIdx.x * ROWS;
  const int l15  = lane & 15;
  const int lh   = lane >> 4;      // 0..3
  const int swz_l = SWZ(lane);
  const int r0   = b0 + (rt << 4); // wave's first row

  // ---- x -> registers: 12 B-frag chunks; lane(l15,lh) = x[r0+l15][32c+8lh .. +7] ----
  const float* xrow = x + (size_t)(r0 + l15) * 385 + (lh << 3);
  s16x8 xf[12];
  #pragma unroll
  for (int c = 0; c < 12; ++c) {
    f32x4 lo = *(const f32x4*)(xrow + c * 32);
    f32x4 hi = *(const f32x4*)(xrow + c * 32 + 4);
    s16x8 v;
    v[0] = (short)bfbits(lo[0]); v[1] = (short)bfbits(lo[1]);
    v[2] = (short)bfbits(lo[2]); v[3] = (short)bfbits(lo[3]);
    v[4] = (short)bfbits(hi[0]); v[5] = (short)bfbits(hi[1]);
    v[6] = (short)bfbits(hi[2]); v[7] = (short)bfbits(hi[3]);
    xf[c] = v;
  }
  const float xv384 = x[(size_t)(r0 + l15) * 385 + 384];

  // ---- GEMM1: 16 f-tiles/wave (ft = fh*16 + t), K=384, barrier-free ----
  #pragma unroll
  for (int t = 0; t < 16; ++t) {
    int ft = (fh << 4) + t;
    f32x4 acc = (f32x4)0.0f;
    #pragma unroll
    for (int c = 0; c < 12; ++c) {
      s16x8 af = *(const s16x8*)(w1f + (((c * 32 + ft) * 64 + lane) << 3));
      acc = MFMA(af, xf[c], acc);
    }
    // epilogue 1: rank-1 + bias + relu -> bf16 B-frag -> h1B
    int fg = (ft << 4) + (lh << 2);
    f32x4 bv = *(const f32x4*)(b1 + fg);
    f32x4 wv = *(const f32x4*)(W1 + 384 * 512 + fg);
    float v0 = fmaxf(acc[0] + bv[0] + wv[0] * xv384, 0.f);
    float v1 = fmaxf(acc[1] + bv[1] + wv[1] * xv384, 0.f);
    float v2 = fmaxf(acc[2] + bv[2] + wv[2] * xv384, 0.f);
    float v3 = fmaxf(acc[3] + bv[3] + wv[3] * xv384, 0.f);
    unsigned plo = (unsigned)bfbits(v0) | ((unsigned)bfbits(v1) << 16);
    unsigned phi = (unsigned)bfbits(v2) | ((unsigned)bfbits(v3) << 16);
    unsigned long long pk = (unsigned long long)plo | ((unsigned long long)phi << 32);
    int khB = ((ft & 1) << 1) + (lh >> 1);
    int so  = (rt << 14) + ((ft >> 1) << 10) + SWZ(l15 + (khB << 4)) + ((lh & 1) << 3);
    *(unsigned long long*)(lds + so) = pk;
  }
  __syncthreads();                         // B1: h1B complete (both f-halves)

  // ---- GEMM2: 8 f2-tiles/wave (ft2 = fh*8 + t), K=512 ----
  unsigned long long h2p[8];
  #pragma unroll
  for (int t = 0; t < 8; ++t) {
    int ft2 = (fh << 3) + t;
    f32x4 acc = (f32x4)0.0f;
    #pragma unroll
    for (int c = 0; c < 16; ++c) {
      s16x8 a2  = *(const s16x8*)(w2f + (((c * 16 + ft2) * 64 + lane) << 3));
      s16x8 bfr = *(const s16x8*)(lds + (rt << 14) + (c << 10) + swz_l);
      acc = MFMA(a2, bfr, acc);
    }
    int fg = (ft2 << 4) + (lh << 2);
    f32x4 bv = *(const f32x4*)(b2 + fg);
    float v0 = fmaxf(acc[0] + bv[0], 0.f);
    float v1 = fmaxf(acc[1] + bv[1], 0.f);
    float v2 = fmaxf(acc[2] + bv[2], 0.f);
    float v3 = fmaxf(acc[3] + bv[3], 0.f);
    unsigned plo = (unsigned)bfbits(v0) | ((unsigned)bfbits(v1) << 16);
    unsigned phi = (unsigned)bfbits(v2) | ((unsigned)bfbits(v3) << 16);
    h2p[t] = (unsigned long long)plo | ((unsigned long long)phi << 32);
  }
  __syncthreads();                         // B2: h1B reads done -> region reusable

  #pragma unroll
  for (int t = 0; t < 8; ++t) {
    int ft2 = (fh << 3) + t;
    int khB = ((ft2 & 1) << 1) + (lh >> 1);
    int so  = (rt << 13) + ((ft2 >> 1) << 10) + SWZ(l15 + (khB << 4)) + ((lh & 1) << 3);
    *(unsigned long long*)(lds + so) = h2p[t];
  }
  __syncthreads();                         // B3: h2B visible

  // head-routing loads issued now; latency hides under GEMM3
  const int hrow = tid >> 4, hj = tid & 15;
  const int head0 = qid[b0 + hrow] * 2 + corr[b0 + hrow];
  const int head1 = qid[b0 + 32 + hrow] * 2 + corr[b0 + 32 + hrow];

  // ---- GEMM3: 6 f3-tiles/wave (ft3 = fh*6 + t), K=256 ----
  #pragma unroll
  for (int t = 0; t < 6; ++t) {
    int ft3 = fh * 6 + t;
    f32x4 acc = (f32x4)0.0f;
    #pragma unroll
    for (int c = 0; c < 8; ++c) {
      s16x8 a3  = *(const s16x8*)(w3f + (((c * 12 + ft3) * 64 + lane) << 3));
      s16x8 bfr = *(const s16x8*)(lds + (rt << 13) + (c << 10) + swz_l);
      acc = MFMA(a3, bfr, acc);
    }
    // epilogue 3 -> h3b [rt][row][200] bf16: lane writes row=l15, f = ft3*16+4lh..+3
    int fg = (ft3 << 4) + (lh << 2);
    f32x4 bv = *(const f32x4*)(b3 + fg);
    float v0 = fmaxf(acc[0] + bv[0], 0.f);
    float v1 = fmaxf(acc[1] + bv[1], 0.f);
    float v2 = fmaxf(acc[2] + bv[2], 0.f);
    float v3 = fmaxf(acc[3] + bv[3], 0.f);
    unsigned plo = (unsigned)bfbits(v0) | ((unsigned)bfbits(v1) << 16);
    unsigned phi = (unsigned)bfbits(v2) | ((unsigned)bfbits(v3) << 16);
    unsigned long long pk = (unsigned long long)plo | ((unsigned long long)phi << 32);
    *(unsigned long long*)(lds + 36864 + rt * 6400 + l15 * 400 + (fg << 1)) = pk;
  }
  __syncthreads();                         // B4: h3b ready

  // ---- head: 2 outputs/thread (rows hrow, 32+hrow) ----
  const unsigned short* h3s = (const unsigned short*)(lds + 36864);
  #pragma unroll
  for (int q = 0; q < 2; ++q) {
    int row  = q * 32 + hrow;
    int head = q ? head1 : head0;
    const unsigned short* wp = whT + ((head * 24) * 16 + hj) * 8;
    const unsigned short* hp = h3s + (row >> 4) * 3200 + (row & 15) * 200;
    float acc = bh[(head << 4) + hj];
    #pragma unroll 6
    for (int fo = 0; fo < 24; ++fo) {
      s16x8 wv = *(const s16x8*)(wp + fo * 128);
      s16x8 hv = *(const s16x8*)(hp + fo * 8);
      #pragma unroll
      for (int e = 0; e < 8; ++e)
        acc += bf2f((unsigned short)wv[e]) * bf2f((unsigned short)hv[e]);
    }
    out[(size_t)(b0 + row) * 16 + hj] = acc;
  }
}

extern "C" void kernel_launch(void* const* d_in, const int* in_sizes, int n_in,
                              void* d_out, int out_size, void* d_ws, size_t ws_size,
                              hipStream_t stream) {
  (void)in_sizes; (void)n_in; (void)out_size; (void)ws_size;
  const float* x  = (const float*)d_in[0];
  const float* W1 = (const float*)d_in[1];
  const float* b1 = (const float*)d_in[2];
  const float* W2 = (const float*)d_in[3];
  const float* b2 = (const float*)d_in[4];
  const float* W3 = (const float*)d_in[5];
  const float* b3 = (const float*)d_in[6];
  const float* Wh = (const float*)d_in[7];
  const float* bh = (const float*)d_in[8];
  const int* qid  = (const int*)d_in[9];
  const int* corr = (const int*)d_in[10];
  float* out = (float*)d_out;

  unsigned short* w1f = (unsigned short*)d_ws;     // 196608 bf16
  unsigned short* w2f = w1f + 196608;              // 131072
  unsigned short* w3f = w2f + 131072;              // 49152
  unsigned short* whT = w3f + 49152;               // 393216   (total ~1.54 MB)

  prep_kernel<<<376, 256, 0, stream>>>(W1, W2, W3, Wh, w1f, w2f, w3f, whT);
  fused_mlp<<<65536 / ROWS, THREADS, 0, stream>>>(x, b1, b2, b3, bh, W1, qid, corr,
                                                  w1f, w2f, w3f, whT, out);
}

// Round 11
// 102.140 us; speedup vs baseline: 2.0625x; 1.4210x over previous
//
#include <hip/hip_runtime.h>
#include <hip/hip_bf16.h>

#define THREADS 1024
#define ROWS 64

typedef __attribute__((ext_vector_type(4))) float f32x4;
typedef __attribute__((ext_vector_type(8))) short s16x8;

__device__ __forceinline__ unsigned short bfbits(float f) {
  __bf16 h = (__bf16)f;
  return __builtin_bit_cast(unsigned short, h);
}
__device__ __forceinline__ float bf2f(unsigned short h) {
  unsigned u = ((unsigned)h) << 16;
  return __builtin_bit_cast(float, u);
}

// ---------------- prep: pack weights into MFMA A-fragment order (bf16) ----------------
// A-frag for mfma_f32_16x16x32_bf16: lane l holds A[m=l&15][k=(l>>4)*8+j], j=0..7
// w1f: [c:12][ft:32][lane:64][8]   (K=384 of W1; k=384 is a rank-1 term in epilogue 1)
// w2f: [c:16][ft:16][lane:64][8]
// w3f: [c: 8][ft:12][lane:64][8]
// whT: [head:128][fo:24][j:16][8] bf16
__global__ void prep_kernel(const float* __restrict__ W1, const float* __restrict__ W2,
                            const float* __restrict__ W3, const float* __restrict__ Wh,
                            unsigned short* __restrict__ w1f, unsigned short* __restrict__ w2f,
                            unsigned short* __restrict__ w3f, unsigned short* __restrict__ whT) {
  int u = blockIdx.x * blockDim.x + threadIdx.x;
  const int U1 = 24576, U2 = 16384, U3 = 6144, U4 = 49152;
  if (u < U1) {                                   // W1 frags
    int lane = u & 63, r = (u >> 6) & 31, c = u >> 11;
    int f  = r * 16 + (lane & 15);
    int kb = c * 32 + ((lane >> 4) << 3);
    s16x8 v;
    #pragma unroll
    for (int j = 0; j < 8; ++j) v[j] = (short)bfbits(W1[(kb + j) * 512 + f]);
    *(s16x8*)(w1f + (u << 3)) = v;
    return;
  }
  u -= U1;
  if (u < U2) {                                   // W2 frags
    int lane = u & 63, r = (u >> 6) & 15, c = u >> 10;
    int f  = r * 16 + (lane & 15);
    int kb = c * 32 + ((lane >> 4) << 3);
    s16x8 v;
    #pragma unroll
    for (int j = 0; j < 8; ++j) v[j] = (short)bfbits(W2[(kb + j) * 256 + f]);
    *(s16x8*)(w2f + (u << 3)) = v;
    return;
  }
  u -= U2;
  if (u < U3) {                                   // W3 frags
    int lane = u & 63, t = u >> 6;
    int c = t / 12, r = t - c * 12;
    int f  = r * 16 + (lane & 15);
    int kb = c * 32 + ((lane >> 4) << 3);
    s16x8 v;
    #pragma unroll
    for (int j = 0; j < 8; ++j) v[j] = (short)bfbits(W3[(kb + j) * 192 + f]);
    *(s16x8*)(w3f + (u << 3)) = v;
    return;
  }
  u -= U3;
  if (u < U4) {                                   // Wh -> [head][fo][j][8]
    int j = u & 15, v2 = u >> 4;
    int fo = v2 % 24, head = v2 / 24;
    s16x8 v;
    #pragma unroll
    for (int i = 0; i < 8; ++i) v[i] = (short)bfbits(Wh[(fo * 8 + i) * 2048 + head * 16 + j]);
    *(s16x8*)(whT + u * 8) = v;
  }
}

// ---------------- fused MLP: R3 structure, 4 barriers, prefetched A-frags ----------------
// 1024 threads (16 waves), 64 rows/block, 1 block/CU. LDS 114688 B:
//   xall @0      (48K, 12 x-chunks)  -> h2f (32K, aliases after B2)
//   h1f  @49152  (64K)               -> h3b [64][200] bf16 (aliases after B3)
// Barriers: B1 stage / B2 h1f vis / B3 h2f vis + h1f reads done / B4 h3b vis.
// Reg discipline: acc <= 32 AGPR, transient staging only, arch side < 64.
#define MFMA(a, b, c) __builtin_amdgcn_mfma_f32_16x16x32_bf16((a), (b), (c), 0, 0, 0)
#define SWZ(lp) (((lp) * 16) ^ ((((lp) >> 4) & 3) << 5))

__global__ __launch_bounds__(THREADS, 4)
void fused_mlp(const float* __restrict__ x,
               const float* __restrict__ b1,
               const float* __restrict__ b2,
               const float* __restrict__ b3,
               const float* __restrict__ bh,
               const float* __restrict__ W1,
               const int* __restrict__ qid,
               const int* __restrict__ corr,
               const unsigned short* __restrict__ w1f,
               const unsigned short* __restrict__ w2f,
               const unsigned short* __restrict__ w3f,
               const unsigned short* __restrict__ whT,
               float* __restrict__ out) {
  __shared__ __align__(16) unsigned char lds[114688];
  unsigned char* xall = lds;                 // x B-frags, then h2f
  unsigned char* h1f  = lds + 49152;         // h1 B-frags, then h3b
  unsigned char* h2f  = lds;
  unsigned char* h3b  = lds + 49152;

  const int tid  = threadIdx.x;
  const int lane = tid & 63;
  const int w    = tid >> 6;       // wave 0..15
  const int b0   = blockIdx.x * ROWS;
  const int l15  = lane & 15;
  const int lh   = lane >> 4;      // 0..3
  const int swz_l = SWZ(lane);

  // ---- one-shot x staging: 3 frags/thread (12 chunks x 256 slots), ONE barrier ----
  {
    f32x4 L[3], H[3];
    int sad[3];
    #pragma unroll
    for (int i = 0; i < 3; ++i) {
      int fi = i * 1024 + tid;     // 0..3071
      int c  = fi >> 8;            // chunk 0..11
      int wi = fi & 255;           // slot within chunk
      int bt = wi >> 6, lp = wi & 63;
      const float* p = x + (size_t)(b0 + (bt << 4) + (lp & 15)) * 385 + c * 32 + ((lp >> 4) << 3);
      L[i] = *(const f32x4*)p;
      H[i] = *(const f32x4*)(p + 4);
      sad[i] = (c << 12) + (bt << 10) + SWZ(lp);
    }
    #pragma unroll
    for (int i = 0; i < 3; ++i) {
      s16x8 v;
      v[0] = (short)bfbits(L[i][0]); v[1] = (short)bfbits(L[i][1]);
      v[2] = (short)bfbits(L[i][2]); v[3] = (short)bfbits(L[i][3]);
      v[4] = (short)bfbits(H[i][0]); v[5] = (short)bfbits(H[i][1]);
      v[6] = (short)bfbits(H[i][2]); v[7] = (short)bfbits(H[i][3]);
      *(s16x8*)(xall + sad[i]) = v;
    }
  }
  __syncthreads();                           // B1: xall staged

  // ---- GEMM1: 2 f-tiles/wave (ft = w*2+a), K=384, barrier-free, depth-1 A-prefetch ----
  f32x4 acc1[2][4];
  #pragma unroll
  for (int a = 0; a < 2; ++a)
    #pragma unroll
    for (int bt = 0; bt < 4; ++bt) acc1[a][bt] = (f32x4)0.0f;

  {
    s16x8 afn0 = *(const s16x8*)(w1f + (((0 * 32 + w * 2 + 0) * 64 + lane) << 3));
    s16x8 afn1 = *(const s16x8*)(w1f + (((0 * 32 + w * 2 + 1) * 64 + lane) << 3));
    #pragma unroll
    for (int c = 0; c < 12; ++c) {
      s16x8 a0 = afn0, a1 = afn1;
      if (c + 1 < 12) {
        afn0 = *(const s16x8*)(w1f + ((((c + 1) * 32 + w * 2 + 0) * 64 + lane) << 3));
        afn1 = *(const s16x8*)(w1f + ((((c + 1) * 32 + w * 2 + 1) * 64 + lane) << 3));
      }
      #pragma unroll
      for (int bt = 0; bt < 4; ++bt) {
        s16x8 bfr = *(const s16x8*)(xall + (c << 12) + (bt << 10) + swz_l);
        acc1[0][bt] = MFMA(a0, bfr, acc1[0][bt]);
        acc1[1][bt] = MFMA(a1, bfr, acc1[1][bt]);
      }
    }
  }

  // epilogue 1: rank-1 (k=384) + bias + relu -> bf16 B-frags -> h1f
  #pragma unroll
  for (int a = 0; a < 2; ++a) {
    int ft = w * 2 + a;
    int fg = (ft << 4) + (lh << 2);
    f32x4 bv = *(const f32x4*)(b1 + fg);
    f32x4 wv = *(const f32x4*)(W1 + 384 * 512 + fg);
    int so = ((ft >> 1) << 12) + SWZ(l15 + ((((ft & 1) << 1) + (lh >> 1)) << 4)) + ((lh & 1) << 3);
    #pragma unroll
    for (int bt = 0; bt < 4; ++bt) {
      float xv = x[(size_t)(b0 + (bt << 4) + l15) * 385 + 384];
      float v0 = fmaxf(acc1[a][bt][0] + bv[0] + wv[0] * xv, 0.f);
      float v1 = fmaxf(acc1[a][bt][1] + bv[1] + wv[1] * xv, 0.f);
      float v2 = fmaxf(acc1[a][bt][2] + bv[2] + wv[2] * xv, 0.f);
      float v3 = fmaxf(acc1[a][bt][3] + bv[3] + wv[3] * xv, 0.f);
      unsigned plo = (unsigned)bfbits(v0) | ((unsigned)bfbits(v1) << 16);
      unsigned phi = (unsigned)bfbits(v2) | ((unsigned)bfbits(v3) << 16);
      unsigned long long pk = (unsigned long long)plo | ((unsigned long long)phi << 32);
      *(unsigned long long*)(h1f + so + (bt << 10)) = pk;
    }
  }
  __syncthreads();                           // B2: h1f visible; xall reads all done

  // ---- GEMM2: 1 f2-tile/wave (ft2 = w), K=512, depth-1 A-prefetch ----
  f32x4 acc2[4];
  #pragma unroll
  for (int bt = 0; bt < 4; ++bt) acc2[bt] = (f32x4)0.0f;

  {
    s16x8 a2n = *(const s16x8*)(w2f + (((0 * 16 + w) * 64 + lane) << 3));
    #pragma unroll
    for (int c = 0; c < 16; ++c) {
      s16x8 a2 = a2n;
      if (c + 1 < 16) a2n = *(const s16x8*)(w2f + ((((c + 1) * 16 + w) * 64 + lane) << 3));
      #pragma unroll
      for (int bt = 0; bt < 4; ++bt) {
        s16x8 bfr = *(const s16x8*)(h1f + (c << 12) + (bt << 10) + swz_l);
        acc2[bt] = MFMA(a2, bfr, acc2[bt]);
      }
    }
  }

  // epilogue 2 -> h2f (@xall region, free since B2)
  {
    int fg = (w << 4) + (lh << 2);
    f32x4 bv = *(const f32x4*)(b2 + fg);
    int so = ((w >> 1) << 12) + SWZ(l15 + ((((w & 1) << 1) + (lh >> 1)) << 4)) + ((lh & 1) << 3);
    #pragma unroll
    for (int bt = 0; bt < 4; ++bt) {
      float v0 = fmaxf(acc2[bt][0] + bv[0], 0.f);
      float v1 = fmaxf(acc2[bt][1] + bv[1], 0.f);
      float v2 = fmaxf(acc2[bt][2] + bv[2], 0.f);
      float v3 = fmaxf(acc2[bt][3] + bv[3], 0.f);
      unsigned plo = (unsigned)bfbits(v0) | ((unsigned)bfbits(v1) << 16);
      unsigned phi = (unsigned)bfbits(v2) | ((unsigned)bfbits(v3) << 16);
      unsigned long long pk = (unsigned long long)plo | ((unsigned long long)phi << 32);
      *(unsigned long long*)(h2f + so + (bt << 10)) = pk;
    }
  }
  __syncthreads();                           // B3: h2f visible; h1f reads all done

  // head routing prefetched; latency hides under GEMM3
  const int hrow = tid >> 4, hj = tid & 15;
  const int gb   = b0 + hrow;
  const int head = qid[gb] * 2 + corr[gb];

  // ---- GEMM3: 12 f3-tiles over waves 0..11, K=256, depth-1 A-prefetch ----
  if (w < 12) {
    f32x4 acc3[4];
    #pragma unroll
    for (int bt = 0; bt < 4; ++bt) acc3[bt] = (f32x4)0.0f;

    s16x8 a3n = *(const s16x8*)(w3f + (((0 * 12 + w) * 64 + lane) << 3));
    #pragma unroll
    for (int c = 0; c < 8; ++c) {
      s16x8 a3 = a3n;
      if (c + 1 < 8) a3n = *(const s16x8*)(w3f + ((((c + 1) * 12 + w) * 64 + lane) << 3));
      #pragma unroll
      for (int bt = 0; bt < 4; ++bt) {
        s16x8 bfr = *(const s16x8*)(h2f + (c << 12) + (bt << 10) + swz_l);
        acc3[bt] = MFMA(a3, bfr, acc3[bt]);
      }
    }

    // epilogue 3 -> h3b [64][200] bf16 (@h1f region, free since B3)
    int fg = (w << 4) + (lh << 2);
    f32x4 bv = *(const f32x4*)(b3 + fg);
    #pragma unroll
    for (int bt = 0; bt < 4; ++bt) {
      int row = (bt << 4) + l15;
      float v0 = fmaxf(acc3[bt][0] + bv[0], 0.f);
      float v1 = fmaxf(acc3[bt][1] + bv[1], 0.f);
      float v2 = fmaxf(acc3[bt][2] + bv[2], 0.f);
      float v3 = fmaxf(acc3[bt][3] + bv[3], 0.f);
      unsigned plo = (unsigned)bfbits(v0) | ((unsigned)bfbits(v1) << 16);
      unsigned phi = (unsigned)bfbits(v2) | ((unsigned)bfbits(v3) << 16);
      unsigned long long pk = (unsigned long long)plo | ((unsigned long long)phi << 32);
      *(unsigned long long*)(h3b + row * 400 + (w << 5) + (lh << 3)) = pk;
    }
  }
  __syncthreads();                           // B4: h3b ready

  // ---- head: 1 output/thread ----
  {
    const unsigned short* wp = whT + ((head * 24) * 16 + hj) * 8;
    const unsigned short* hp = (const unsigned short*)h3b + hrow * 200;
    float acc = bh[(head << 4) + hj];
    #pragma unroll 6
    for (int fo = 0; fo < 24; ++fo) {
      s16x8 wv = *(const s16x8*)(wp + fo * 128);
      s16x8 hv = *(const s16x8*)(hp + fo * 8);
      #pragma unroll
      for (int e = 0; e < 8; ++e)
        acc += bf2f((unsigned short)wv[e]) * bf2f((unsigned short)hv[e]);
    }
    out[(size_t)gb * 16 + hj] = acc;
  }
}

extern "C" void kernel_launch(void* const* d_in, const int* in_sizes, int n_in,
                              void* d_out, int out_size, void* d_ws, size_t ws_size,
                              hipStream_t stream) {
  (void)in_sizes; (void)n_in; (void)out_size; (void)ws_size;
  const float* x  = (const float*)d_in[0];
  const float* W1 = (const float*)d_in[1];
  const float* b1 = (const float*)d_in[2];
  const float* W2 = (const float*)d_in[3];
  const float* b2 = (const float*)d_in[4];
  const float* W3 = (const float*)d_in[5];
  const float* b3 = (const float*)d_in[6];
  const float* Wh = (const float*)d_in[7];
  const float* bh = (const float*)d_in[8];
  const int* qid  = (const int*)d_in[9];
  const int* corr = (const int*)d_in[10];
  float* out = (float*)d_out;

  unsigned short* w1f = (unsigned short*)d_ws;     // 196608 bf16
  unsigned short* w2f = w1f + 196608;              // 131072
  unsigned short* w3f = w2f + 131072;              // 49152
  unsigned short* whT = w3f + 49152;               // 393216   (total ~1.54 MB)

  prep_kernel<<<376, 256, 0, stream>>>(W1, W2, W3, Wh, w1f, w2f, w3f, whT);
  fused_mlp<<<65536 / ROWS, THREADS, 0, stream>>>(x, b1, b2, b3, bh, W1, qid, corr,
                                                  w1f, w2f, w3f, whT, out);
}